// Round 15
// baseline (409.409 us; speedup 1.0000x reference)
//
#include <hip/hip_runtime.h>
#include <hip/hip_fp16.h>

// Problem constants (match reference)
#define NRAYS 1048576
#define NV 32
#define ND 32
#define NF 6
#define NK 13  // 2F+1

typedef _Float16 h2 __attribute__((ext_vector_type(2)));
typedef float f4 __attribute__((ext_vector_type(4)));

__device__ __forceinline__ float fdot2acc(h2 a, h2 b, float c) {
#if __has_builtin(__builtin_amdgcn_fdot2)
    return __builtin_amdgcn_fdot2(a, b, c, false);
#else
    return c + (float)a.x * (float)b.x + (float)a.y * (float)b.y;
#endif
}

__device__ __forceinline__ h2 pack2(float a, float b) {
#if __has_builtin(__builtin_amdgcn_cvt_pkrtz)
    return __builtin_bit_cast(h2, __builtin_amdgcn_cvt_pkrtz(a, b));
#else
    h2 r; r.x = (_Float16)a; r.y = (_Float16)b; return r;
#endif
}

__device__ __forceinline__ float hwsin(float rev) {
#if __has_builtin(__builtin_amdgcn_sinf)
    return __builtin_amdgcn_sinf(rev);
#else
    return __sinf(6.28318530717958647692f * rev);
#endif
}
__device__ __forceinline__ float hwcos(float rev) {
#if __has_builtin(__builtin_amdgcn_cosf)
    return __builtin_amdgcn_cosf(rev);
#else
    return __cosf(6.28318530717958647692f * rev);
#endif
}

__device__ __forceinline__ void make_basis(float t, h2 bp[7]) {
    float sv[NF], cv[NF];
    sv[0] = hwsin(0.5f * t);
    cv[0] = hwcos(0.5f * t);
#pragma unroll
    for (int j = 1; j < NF; ++j) {
        float sj = sv[j - 1], cj = cv[j - 1];
        sv[j] = 2.f * sj * cj;
        cv[j] = fmaf(-2.f * sj, sj, 1.f);
    }
    bp[0] = pack2(1.0f, sv[0]);
    bp[1] = pack2(sv[1], sv[2]);
    bp[2] = pack2(sv[3], sv[4]);
    bp[3] = pack2(sv[5], cv[0]);
    bp[4] = pack2(cv[1], cv[2]);
    bp[5] = pack2(cv[3], cv[4]);
    bp[6] = pack2(cv[5], 0.0f);  // pad half must be 0
}

// ---------------------------------------------------------------------------
// Kernel A: pack f32 weights into the v&7-XOR-swizzled f16 image (see R5).
__global__ void pack_weights_kernel(const float* __restrict__ weights,
                                    unsigned* __restrict__ wpack)
{
    int j = blockIdx.x * 256 + threadIdx.x;  // 0 .. 7167 (dwords)
    if (j >= NV * 7 * 32) return;
    int v = j / 224;
    int r = j - v * 224;
    int i = r >> 5;
    int c = r & 31;
    int pos = c >> 2;
    int e = c & 3;
    int q = pos ^ (v & 7);
    int d = 4 * q + e;
    float w0 = weights[v * (ND * NK) + d * NK + 2 * i];
    float w1 = (2 * i + 1 < NK) ? weights[v * (ND * NK) + d * NK + 2 * i + 1] : 0.f;
    wpack[j] = __builtin_bit_cast(unsigned, pack2(w0, w1));
}

// ---------------------------------------------------------------------------
// Production: R11 structure verbatim (best known, 33.8us) with NONTEMPORAL
// stores (the untested A/B; MODE1 proved nt+reads sustains 5.1 TB/s).
__global__ __launch_bounds__(256, 5) void VideoEmbedding_kernel(
    const float* __restrict__ times,
    const int* __restrict__ vids,
    const unsigned* __restrict__ wpack,
    float* __restrict__ out)
{
    __shared__ _Float16 wl[NV * 7 * ND * 2];   // 28672 B
    __shared__ float s_t[512];                 // 2048 B
    __shared__ unsigned char s_v[512];         // 512 B

    const int tid = threadIdx.x;
    const int rbase = blockIdx.x * 512;

    uint4 wst[7];
    {
        const uint4* src = reinterpret_cast<const uint4*>(wpack);
#pragma unroll
        for (int j = 0; j < 7; ++j)
            wst[j] = src[tid + j * 256];
    }
    const float t0 = times[rbase + tid];
    const float t1 = times[rbase + 256 + tid];
    const int v0i = vids[rbase + tid];
    const int v1i = vids[rbase + 256 + tid];

    {
        uint4* dst = reinterpret_cast<uint4*>(wl);
#pragma unroll
        for (int j = 0; j < 7; ++j)
            dst[tid + j * 256] = wst[j];
    }
    s_t[tid] = t0;
    s_t[tid + 256] = t1;
    s_v[tid] = (unsigned char)v0i;
    s_v[tid + 256] = (unsigned char)v1i;
    __syncthreads();

    const int q = tid & 7;
    const int g = tid >> 3;

    uint4 wA[7], wB[7];
    {
        const int v = s_v[g];
        const unsigned b = (unsigned)v * 448u + (unsigned)(q ^ (v & 7)) * 8u;
#pragma unroll
        for (int i = 0; i < 7; ++i)
            wA[i] = *reinterpret_cast<const uint4*>(&wl[b + i * 64]);
    }

#define ITER(P, WCUR, WNEXT)                                                  \
    {                                                                         \
        if ((P) < 15) {                                                       \
            const int nv = s_v[((P) + 1) * 32 + g];                           \
            const unsigned nb =                                               \
                (unsigned)nv * 448u + (unsigned)(q ^ (nv & 7)) * 8u;          \
            _Pragma("unroll")                                                 \
            for (int i = 0; i < 7; ++i)                                       \
                WNEXT[i] = *reinterpret_cast<const uint4*>(&wl[nb + i * 64]); \
        }                                                                     \
        const float t = s_t[(P) * 32 + g];                                    \
        h2 bp[7];                                                             \
        make_basis(t, bp);                                                    \
        float a0 = 0.f, a1 = 0.f, a2 = 0.f, a3 = 0.f;                         \
        _Pragma("unroll")                                                     \
        for (int i = 0; i < 7; ++i) {                                         \
            a0 = fdot2acc(__builtin_bit_cast(h2, WCUR[i].x), bp[i], a0);      \
            a1 = fdot2acc(__builtin_bit_cast(h2, WCUR[i].y), bp[i], a1);      \
            a2 = fdot2acc(__builtin_bit_cast(h2, WCUR[i].z), bp[i], a2);      \
            a3 = fdot2acc(__builtin_bit_cast(h2, WCUR[i].w), bp[i], a3);      \
        }                                                                     \
        f4 res;                                                               \
        res.x = a0; res.y = a1; res.z = a2; res.w = a3;                       \
        __builtin_nontemporal_store(res,                                      \
            reinterpret_cast<f4*>(out) + (size_t)(rbase + (P) * 32 + g) * 8 + q); \
    }

    for (int p = 0; p < 16; p += 2) {
        ITER(p, wA, wB)
        ITER(p + 1, wB, wA)
    }
#undef ITER
}

// ---------------------------------------------------------------------------
// Shadow 1: PURE plain f4 stores, exact production addressing/grid.
__global__ __launch_bounds__(256, 5) void shadow_store(
    f4* __restrict__ o, int reps)
{
    const int tid = threadIdx.x;
    const int q = tid & 7;
    const int g = tid >> 3;
    const int rbase = blockIdx.x * 512;
    f4 val;
    val.x = (float)tid; val.y = 1.f; val.z = 2.f; val.w = 3.f;
    for (int r = 0; r < reps; ++r) {
#pragma unroll
        for (int p = 0; p < 16; ++p)
            o[(size_t)(rbase + p * 32 + g) * 8 + q] = val;
        val.x += 1.0f;  // keep reps distinct
    }
}

// ---------------------------------------------------------------------------
// Shadow 2: plain stores + per-iter t/vid global reads (read-write mix).
__global__ __launch_bounds__(256, 5) void shadow_store_r(
    const float* __restrict__ times,
    const int* __restrict__ vids,
    f4* __restrict__ o, int reps)
{
    const int tid = threadIdx.x;
    const int q = tid & 7;
    const int g = tid >> 3;
    const int rbase = blockIdx.x * 512;
    for (int r = 0; r < reps; ++r) {
#pragma unroll 4
        for (int p = 0; p < 16; ++p) {
            const int idx = rbase + p * 32 + g;
            const float t = times[idx];
            const int v = vids[idx];
            f4 val;
            val.x = t + (float)v + (float)r;
            val.y = t; val.z = (float)v; val.w = 0.f;
            o[(size_t)idx * 8 + q] = val;
        }
    }
}

// ---------------------------------------------------------------------------
// Shadow 3: plain stores + dbuf'd 7x ds_read_b128 (synthetic vids, NO global
// reads in loop) — isolates the LDS(+)store combination.
__global__ __launch_bounds__(256, 5) void shadow_store_ds(
    const unsigned* __restrict__ wpack,
    f4* __restrict__ o, int reps)
{
    __shared__ _Float16 wl[NV * 7 * ND * 2];
    const int tid = threadIdx.x;
    {
        const uint4* src = reinterpret_cast<const uint4*>(wpack);
        uint4* dst = reinterpret_cast<uint4*>(wl);
#pragma unroll
        for (int j = 0; j < 7; ++j)
            dst[tid + j * 256] = src[tid + j * 256];
    }
    __syncthreads();

    const int q = tid & 7;
    const int g = tid >> 3;
    const int rbase = blockIdx.x * 512;

    for (int r = 0; r < reps; ++r) {
        uint4 wA[7], wB[7];
        {
            const int v = (g * 5 + blockIdx.x + r) & 31;
            const unsigned b = (unsigned)v * 448u + (unsigned)(q ^ (v & 7)) * 8u;
#pragma unroll
            for (int i = 0; i < 7; ++i)
                wA[i] = *reinterpret_cast<const uint4*>(&wl[b + i * 64]);
        }
#define SITER(P, WCUR, WNEXT)                                                 \
        {                                                                     \
            if ((P) < 15) {                                                   \
                const int nv = (((P) + 1) * 37 + g * 5 + blockIdx.x + r) & 31;\
                const unsigned nb =                                           \
                    (unsigned)nv * 448u + (unsigned)(q ^ (nv & 7)) * 8u;      \
                _Pragma("unroll")                                             \
                for (int i = 0; i < 7; ++i)                                   \
                    WNEXT[i] =                                                \
                        *reinterpret_cast<const uint4*>(&wl[nb + i * 64]);    \
            }                                                                 \
            unsigned x0 = 0u, x1 = 0u, x2 = 0u, x3 = 0u;                      \
            _Pragma("unroll")                                                 \
            for (int i = 0; i < 7; ++i) {                                     \
                x0 ^= WCUR[i].x; x1 ^= WCUR[i].y;                             \
                x2 ^= WCUR[i].z; x3 ^= WCUR[i].w;                             \
            }                                                                 \
            f4 res;                                                           \
            res.x = __builtin_bit_cast(float, x0 + (unsigned)r);              \
            res.y = __builtin_bit_cast(float, x1);                            \
            res.z = __builtin_bit_cast(float, x2);                            \
            res.w = __builtin_bit_cast(float, x3);                            \
            o[(size_t)(rbase + (P) * 32 + g) * 8 + q] = res;                  \
        }
        for (int p = 0; p < 16; p += 2) {
            SITER(p, wA, wB)
            SITER(p + 1, wB, wA)
        }
#undef SITER
    }
}

extern "C" void kernel_launch(void* const* d_in, const int* in_sizes, int n_in,
                              void* d_out, int out_size, void* d_ws, size_t ws_size,
                              hipStream_t stream) {
    const float* times = (const float*)d_in[0];
    const int* vids = (const int*)d_in[1];
    const float* weights = (const float*)d_in[2];
    float* out = (float*)d_out;
    unsigned* wpack = (unsigned*)d_ws;
    f4* wsout = (f4*)((char*)d_ws + (size_t)(16u << 20));

    hipLaunchKernelGGL(pack_weights_kernel, dim3(28), dim3(256), 0, stream,
                       weights, wpack);
    hipLaunchKernelGGL(VideoEmbedding_kernel, dim3(2048), dim3(256), 0, stream,
                       times, vids, wpack, out);
    hipLaunchKernelGGL(shadow_store, dim3(2048), dim3(256), 0, stream,
                       wsout, 10);
    hipLaunchKernelGGL(shadow_store_r, dim3(2048), dim3(256), 0, stream,
                       times, vids, wsout, 10);
    hipLaunchKernelGGL(shadow_store_ds, dim3(2048), dim3(256), 0, stream,
                       wpack, wsout, 8);
}

// Round 16
// 33.974 us; speedup vs baseline: 12.0506x; 12.0506x over previous
//
#include <hip/hip_runtime.h>
#include <hip/hip_fp16.h>

// Problem constants (match reference)
#define NRAYS 1048576
#define NV 32
#define ND 32
#define NF 6
#define NK 13  // 2F+1

typedef _Float16 h2 __attribute__((ext_vector_type(2)));
typedef float f4 __attribute__((ext_vector_type(4)));

__device__ __forceinline__ float fdot2acc(h2 a, h2 b, float c) {
#if __has_builtin(__builtin_amdgcn_fdot2)
    return __builtin_amdgcn_fdot2(a, b, c, false);
#else
    return c + (float)a.x * (float)b.x + (float)a.y * (float)b.y;
#endif
}

__device__ __forceinline__ h2 pack2(float a, float b) {
#if __has_builtin(__builtin_amdgcn_cvt_pkrtz)
    return __builtin_bit_cast(h2, __builtin_amdgcn_cvt_pkrtz(a, b));
#else
    h2 r; r.x = (_Float16)a; r.y = (_Float16)b; return r;
#endif
}

__device__ __forceinline__ float hwsin(float rev) {
#if __has_builtin(__builtin_amdgcn_sinf)
    return __builtin_amdgcn_sinf(rev);
#else
    return __sinf(6.28318530717958647692f * rev);
#endif
}
__device__ __forceinline__ float hwcos(float rev) {
#if __has_builtin(__builtin_amdgcn_cosf)
    return __builtin_amdgcn_cosf(rev);
#else
    return __cosf(6.28318530717958647692f * rev);
#endif
}

__device__ __forceinline__ void make_basis(float t, h2 bp[7]) {
    float sv[NF], cv[NF];
    sv[0] = hwsin(0.5f * t);
    cv[0] = hwcos(0.5f * t);
#pragma unroll
    for (int j = 1; j < NF; ++j) {
        float sj = sv[j - 1], cj = cv[j - 1];
        sv[j] = 2.f * sj * cj;
        cv[j] = fmaf(-2.f * sj, sj, 1.f);
    }
    bp[0] = pack2(1.0f, sv[0]);
    bp[1] = pack2(sv[1], sv[2]);
    bp[2] = pack2(sv[3], sv[4]);
    bp[3] = pack2(sv[5], cv[0]);
    bp[4] = pack2(cv[1], cv[2]);
    bp[5] = pack2(cv[3], cv[4]);
    bp[6] = pack2(cv[5], 0.0f);  // pad half must be 0
}

// ---------------------------------------------------------------------------
// Kernel A: pack f32 weights into the v&7-XOR-swizzled f16 image (see R5).
// dword idx = v*224 + i*32 + pos*4 + e; chunk at pos holds d-quad pos^(v&7).
__global__ void pack_weights_kernel(const float* __restrict__ weights,
                                    unsigned* __restrict__ wpack)
{
    int j = blockIdx.x * 256 + threadIdx.x;  // 0 .. 7167 (dwords)
    if (j >= NV * 7 * 32) return;
    int v = j / 224;
    int r = j - v * 224;
    int i = r >> 5;
    int c = r & 31;
    int pos = c >> 2;
    int e = c & 3;
    int q = pos ^ (v & 7);
    int d = 4 * q + e;
    float w0 = weights[v * (ND * NK) + d * NK + 2 * i];
    float w1 = (2 * i + 1 < NK) ? weights[v * (ND * NK) + d * NK + 2 * i + 1] : 0.f;
    wpack[j] = __builtin_bit_cast(unsigned, pack2(w0, w1));
}

// ---------------------------------------------------------------------------
// Main kernel — OCCUPANCY round (R15 diagnosis: shadow_store_r hit the 6.75
// TB/s store roofline at 76% occupancy; production is stuck at 20 waves/CU
// because 256-thread blocks cap at 5 blocks x 28.7KB LDS).
// 512-thread blocks, 4 blocks/CU (135 KB LDS), __launch_bounds__(512,8)
// forces VGPR<=64 -> 32 waves/CU = 100% wave capacity. No weight reg dbuf
// (TLP replaces ILP), LDS-direct weight reads, x8-redundant basis (16.6us
// VALU < 20.4us store floor), plain f4 stores.
__global__ __launch_bounds__(512, 8) void VideoEmbedding_kernel(
    const float* __restrict__ times,
    const int* __restrict__ vids,
    const unsigned* __restrict__ wpack,
    float* __restrict__ out)
{
    __shared__ _Float16 wl[NV * 7 * ND * 2];   // 28672 B
    __shared__ float s_t[1024];                //  4096 B
    __shared__ unsigned char s_v[1024];        //  1024 B -> 33792 B total

    const int tid = threadIdx.x;
    const int rbase = blockIdx.x * 1024;

    // prologue: stage weights + t/vid, one barrier
    {
        const uint4* src = reinterpret_cast<const uint4*>(wpack);
        uint4* dst = reinterpret_cast<uint4*>(wl);
#pragma unroll
        for (int j = 0; j < 4; ++j) {
            int idx = tid + j * 512;
            if (idx < 1792) dst[idx] = src[idx];
        }
    }
    s_t[tid] = times[rbase + tid];
    s_t[tid + 512] = times[rbase + 512 + tid];
    s_v[tid] = (unsigned char)vids[rbase + tid];
    s_v[tid + 512] = (unsigned char)vids[rbase + 512 + tid];
    __syncthreads();

    const int q = tid & 7;
    const int g = tid >> 3;  // ray-group 0..63

    for (int p = 0; p < 16; ++p) {
        const int slot = p * 64 + g;
        const float t = s_t[slot];       // 8-lane broadcast
        const int v = s_v[slot];

        h2 bp[7];
        make_basis(t, bp);

        const unsigned base =
            (unsigned)v * 448u + (unsigned)(q ^ (v & 7)) * 8u;  // half index
        float a0 = 0.f, a1 = 0.f, a2 = 0.f, a3 = 0.f;
#pragma unroll
        for (int i = 0; i < 7; ++i) {
            uint4 w = *reinterpret_cast<const uint4*>(&wl[base + i * 64]);
            a0 = fdot2acc(__builtin_bit_cast(h2, w.x), bp[i], a0);
            a1 = fdot2acc(__builtin_bit_cast(h2, w.y), bp[i], a1);
            a2 = fdot2acc(__builtin_bit_cast(h2, w.z), bp[i], a2);
            a3 = fdot2acc(__builtin_bit_cast(h2, w.w), bp[i], a3);
        }

        f4 res;
        res.x = a0; res.y = a1; res.z = a2; res.w = a3;
        reinterpret_cast<f4*>(out)[(size_t)(rbase + slot) * 8 + q] = res;
    }
}

extern "C" void kernel_launch(void* const* d_in, const int* in_sizes, int n_in,
                              void* d_out, int out_size, void* d_ws, size_t ws_size,
                              hipStream_t stream) {
    const float* times = (const float*)d_in[0];
    const int* vids = (const int*)d_in[1];
    const float* weights = (const float*)d_in[2];
    float* out = (float*)d_out;
    unsigned* wpack = (unsigned*)d_ws;

    hipLaunchKernelGGL(pack_weights_kernel, dim3(28), dim3(256), 0, stream,
                       weights, wpack);
    // 1024 blocks x 1024 contiguous rays; 4 blocks/CU, 32 waves/CU.
    hipLaunchKernelGGL(VideoEmbedding_kernel, dim3(1024), dim3(512), 0, stream,
                       times, vids, wpack, out);
}